// Round 1
// baseline (3664.864 us; speedup 1.0000x reference)
//
#include <hip/hip_runtime.h>
#include <stdint.h>
#include <stddef.h>

#define NN 25000     // nodes
#define NE 100000    // edges
#define EPAD 100096  // 782*128, edge count padded for MFMA tiles
#define FEAT 16
#define DD 64
#define NGG 512
#define NJ 1024
#define NS 2048
#define NO 105
#define SLOPE 0.01f

typedef short bf8 __attribute__((ext_vector_type(8)));   // 8 bf16 raw bits (4 VGPR)
typedef float f32x4 __attribute__((ext_vector_type(4)));

__device__ __forceinline__ float lk(float v){ return v > 0.f ? v : SLOPE*v; }
__device__ __forceinline__ unsigned short f2bf(float f){
  unsigned int x = __float_as_uint(f);
  x += 0x7fffu + ((x>>16)&1u);           // round-to-nearest-even
  return (unsigned short)(x>>16);
}
__device__ __forceinline__ float bf2f(unsigned short u){ return __uint_as_float(((unsigned int)u)<<16); }
__device__ __forceinline__ float sg(float x){ return 1.f/(1.f+expf(-x)); }
// order-preserving float<->uint encoding for atomicMax-based segment max
__device__ __forceinline__ unsigned fenc(float f){ unsigned u = __float_as_uint(f); return (u & 0x80000000u) ? ~u : (u | 0x80000000u); }
__device__ __forceinline__ float fdec(unsigned k){ unsigned u = (k & 0x80000000u) ? (k ^ 0x80000000u) : ~k; return __uint_as_float(u); }

// ---------- setup kernels ----------

// out = leaky(x @ lin0_w.T + lin0_b); wave per node, lane = output channel
__global__ __launch_bounds__(256) void k_lin0(const float* __restrict__ x, const float* __restrict__ w,
                       const float* __restrict__ b, float* __restrict__ h){
  int wid = (blockIdx.x*blockDim.x + threadIdx.x) >> 6;
  int lane = threadIdx.x & 63;
  if (wid >= NN) return;
  float xv = lane < FEAT ? x[wid*FEAT + lane] : 0.f;
  float acc = b[lane];
  #pragma unroll
  for (int f=0; f<FEAT; ++f) acc += __shfl(xv, f) * w[lane*FEAT + f];
  h[wid*DD + lane] = lk(acc);
}

// e1 = bf16(leaky(edge_attr @ net1_w.T + net1_b)); thread per (e,k); zero-pad tail edges
__global__ __launch_bounds__(256) void k_e1(const float* __restrict__ ea, const float* __restrict__ w,
                     const float* __restrict__ b, unsigned short* __restrict__ e1){
  int t = blockIdx.x*blockDim.x + threadIdx.x;   // t = e*64 + k
  int e = t >> 6, k = t & 63;
  float acc = 0.f;
  if (e < NE){
    acc = b[k];
    #pragma unroll
    for (int a=0; a<4; ++a) acc += ea[e*4+a] * w[k*4+a];
    acc = lk(acc);
  }
  e1[t] = f2bf(acc);
}

// bf16 cast of net2_w [4096][64] (kept in [col][k] layout = MFMA B operand, k contiguous)
__global__ __launch_bounds__(256) void k_cast(const float* __restrict__ w, unsigned short* __restrict__ o){
  int t = blockIdx.x*blockDim.x + threadIdx.x;
  o[t] = f2bf(w[t]);
}

// generic transpose: T[c*R + r] = M[r*C + c]
__global__ __launch_bounds__(256) void k_tr(const float* __restrict__ m, float* __restrict__ t, int R, int C){
  int i = blockIdx.x*blockDim.x + threadIdx.x;
  if (i >= R*C) return;
  int r = i / C, c = i - r*C;
  t[c*R + r] = m[i];
}

__global__ __launch_bounds__(256) void k_deg(const int* __restrict__ dst, float* __restrict__ deg){
  int e = blockIdx.x*blockDim.x + threadIdx.x;
  if (e < NE) atomicAdd(&deg[dst[e]], 1.f);
}
__global__ __launch_bounds__(256) void k_invd(float* __restrict__ d){
  int n = blockIdx.x*blockDim.x + threadIdx.x;
  if (n < NN) d[n] = d[n] > 0.f ? 1.f/d[n] : 0.f;
}

// ---------- Wedge GEMM: wedge[e, col] = bf16( sum_k e1[e,k]*W2[col,k] + b2[col] ) ----------
// block = 4 waves; block tile 128 edges x 64 cols; wave w: edges [w*32, w*32+32) x 64 cols
// MFMA 16x16x32 bf16: A row = lane&15, k = 32*ks + 8*(lane>>4)+j ; B col = lane&15 (same k packing)
// C/D: col = lane&15, row = (lane>>4)*4 + j   [HW-verified layout]
__global__ __launch_bounds__(256) void k_gemm(const unsigned short* __restrict__ e1,
                                              const unsigned short* __restrict__ w2,
                                              const float* __restrict__ b2,
                                              unsigned short* __restrict__ wedge, int e0){
  int lane = threadIdx.x & 63;
  int wv = threadIdx.x >> 6;
  int erel = blockIdx.x*128 + wv*32;       // edge base relative to e0 (chunk-local)
  int eglb = e0 + erel;                    // global edge base
  int cbase = blockIdx.y*64;
  int r16 = lane & 15, kg = lane >> 4;

  bf8 a[2][2];
  #pragma unroll
  for (int m=0; m<2; ++m)
    #pragma unroll
    for (int k=0; k<2; ++k)
      a[m][k] = *(const bf8*)(e1 + (size_t)(eglb + m*16 + r16)*64 + k*32 + kg*8);

  f32x4 acc[2][4];
  #pragma unroll
  for (int m=0; m<2; ++m)
    #pragma unroll
    for (int n=0; n<4; ++n)
      acc[m][n] = (f32x4){0.f,0.f,0.f,0.f};

  #pragma unroll
  for (int n=0; n<4; ++n){
    #pragma unroll
    for (int k=0; k<2; ++k){
      bf8 bf = *(const bf8*)(w2 + (size_t)(cbase + n*16 + r16)*64 + k*32 + kg*8);
      #pragma unroll
      for (int m=0; m<2; ++m)
        acc[m][n] = __builtin_amdgcn_mfma_f32_16x16x32_bf16(a[m][k], bf, acc[m][n], 0, 0, 0);
    }
  }
  #pragma unroll
  for (int m=0; m<2; ++m){
    #pragma unroll
    for (int n=0; n<4; ++n){
      int col = cbase + n*16 + r16;
      float bb = b2[col];
      int er = erel + m*16 + kg*4;
      #pragma unroll
      for (int j=0; j<4; ++j)
        wedge[(size_t)(er + j)*4096 + col] = f2bf(acc[m][n][j] + bb);
    }
  }
}

// ---------- per-edge message + scatter: aggr[dst] += h[src] @ Wedge[e] ----------
// wave per edge. Wedge row = 4096 bf16 (8KB). 8 steps, each: contiguous 1KB wave-load
// lane covers row i=(st*8 + lane>>3), cols (lane&7)*8..+7; butterfly-reduce over lane stride 8.
__global__ __launch_bounds__(256) void k_msg(const unsigned short* __restrict__ wedge,
                                             const float* __restrict__ h,
                                             const int* __restrict__ src, const int* __restrict__ dst,
                                             float* __restrict__ aggr, int e0, int ecount){
  int wid = (blockIdx.x*blockDim.x + threadIdx.x) >> 6;   // chunk-local edge index
  int lane = threadIdx.x & 63;
  int e = e0 + wid;
  if (wid >= ecount || e >= NE) return;
  int s = src[e], d2 = dst[e];
  float hreg = h[(size_t)s*DD + lane];
  const unsigned short* wrow = wedge + (size_t)wid*4096;
  int rgrp = lane >> 3, cgrp = lane & 7;
  float acc[8] = {0,0,0,0,0,0,0,0};
  #pragma unroll
  for (int st=0; st<8; ++st){
    bf8 wvv = *(const bf8*)(wrow + st*512 + lane*8);
    float hv = __shfl(hreg, st*8 + rgrp);
    #pragma unroll
    for (int j=0; j<8; ++j)
      acc[j] += hv * bf2f((unsigned short)wvv[j]);
  }
  #pragma unroll
  for (int off=8; off<64; off<<=1)
    #pragma unroll
    for (int j=0; j<8; ++j) acc[j] += __shfl_xor(acc[j], off);
  // lane writes col = cgrp*8 + rgrp with value acc[rgrp]
  float v = acc[0];
  #pragma unroll
  for (int j=1; j<8; ++j) v = (rgrp == j) ? acc[j] : v;
  atomicAdd(&aggr[(size_t)d2*DD + cgrp*8 + rgrp], v);
}

// ---------- fused NNConv-root + GRU: h = GRU(leaky(aggr*invd + h@conv_root + cb), h) ----------
#define NB 8
__global__ __launch_bounds__(256) void k_gru(float* __restrict__ h, const float* __restrict__ aggr,
                      const float* __restrict__ invd,
                      const float* __restrict__ cr, const float* __restrict__ cb,
                      const float* __restrict__ wihT, const float* __restrict__ whhT,
                      const float* __restrict__ bih, const float* __restrict__ bhh){
  int wid = (blockIdx.x*blockDim.x + threadIdx.x) >> 6;
  int lane = threadIdx.x & 63;
  int nb0 = wid * NB;
  if (nb0 >= NN) return;
  int cnt = NN - nb0 < NB ? NN - nb0 : NB;

  float hreg[NB], mreg[NB], mac[NB];
  #pragma unroll
  for (int t=0; t<NB; ++t){ hreg[t] = (t<cnt) ? h[(size_t)(nb0+t)*DD + lane] : 0.f; mac[t]=0.f; }
  for (int i=0; i<DD; ++i){
    float crv = cr[i*DD + lane];
    #pragma unroll
    for (int t=0; t<NB; ++t) mac[t] += __shfl(hreg[t], i) * crv;
  }
  #pragma unroll
  for (int t=0; t<NB; ++t){
    if (t < cnt){
      float id = invd[nb0+t];
      mreg[t] = lk(aggr[(size_t)(nb0+t)*DD + lane]*id + mac[t] + cb[lane]);
    } else mreg[t] = 0.f;
  }
  float air[NB]={}, aiz[NB]={}, ain[NB]={}, ahr[NB]={}, ahz[NB]={}, ahn[NB]={};
  for (int i=0; i<DD; ++i){
    float w0 = wihT[i*192 + lane], w1 = wihT[i*192 + 64 + lane], w2 = wihT[i*192 + 128 + lane];
    float v0 = whhT[i*192 + lane], v1 = whhT[i*192 + 64 + lane], v2 = whhT[i*192 + 128 + lane];
    #pragma unroll
    for (int t=0; t<NB; ++t){
      float mi = __shfl(mreg[t], i), hi = __shfl(hreg[t], i);
      air[t] += mi*w0; aiz[t] += mi*w1; ain[t] += mi*w2;
      ahr[t] += hi*v0; ahz[t] += hi*v1; ahn[t] += hi*v2;
    }
  }
  float bi0 = bih[lane], bi1 = bih[64+lane], bi2 = bih[128+lane];
  float bh0 = bhh[lane], bh1 = bhh[64+lane], bh2 = bhh[128+lane];
  #pragma unroll
  for (int t=0; t<NB; ++t){
    if (t < cnt){
      float r = sg(air[t]+bi0 + ahr[t]+bh0);
      float z = sg(aiz[t]+bi1 + ahz[t]+bh1);
      float n = tanhf(ain[t]+bi2 + r*(ahn[t]+bh2));
      h[(size_t)(nb0+t)*DD + lane] = (1.f - z)*n + z*hreg[t];
    }
  }
}

// ---------- heads ----------
// jbond row kernel: wave per gathered atom row (2048)
__global__ __launch_bounds__(256) void k_jbond(const float* __restrict__ h, const int* __restrict__ idx,
                        const float* __restrict__ w1T, const float* __restrict__ b1,
                        const float* __restrict__ w2, const float* __restrict__ b2,
                        float* __restrict__ jtmp){
  int wid = (blockIdx.x*blockDim.x + threadIdx.x) >> 6;
  int lane = threadIdx.x & 63;
  if (wid >= NJ*2) return;
  int a = idx[wid];
  float f = h[(size_t)a*DD + lane];
  float acc = b1[lane];
  for (int i=0; i<DD; ++i) acc += __shfl(f, i) * w1T[i*DD + lane];
  float p = lk(acc) * w2[lane];
  #pragma unroll
  for (int off=32; off; off>>=1) p += __shfl_xor(p, off);
  if (lane == 0) jtmp[wid] = p + b2[0];
}
__global__ __launch_bounds__(256) void k_jmean(const float* __restrict__ jtmp, float* __restrict__ o){
  int j = blockIdx.x*blockDim.x + threadIdx.x;
  if (j < NJ) o[j] = 0.5f*(jtmp[2*j] + jtmp[2*j+1]);
}
__global__ __launch_bounds__(256) void k_stem1(const float* __restrict__ h, const int* __restrict__ idx,
                        const float* __restrict__ w1T, const float* __restrict__ b1,
                        float* __restrict__ st1){
  int wid = (blockIdx.x*blockDim.x + threadIdx.x) >> 6;
  int lane = threadIdx.x & 63;
  if (wid >= NS) return;
  int a = idx[wid];
  float f = h[(size_t)a*DD + lane];
  float acc = b1[lane];
  for (int i=0; i<DD; ++i) acc += __shfl(f, i) * w1T[i*DD + lane];
  st1[(size_t)wid*DD + lane] = lk(acc);
}
__global__ __launch_bounds__(256) void k_stem2(const float* __restrict__ st1, const float* __restrict__ w2,
                        const float* __restrict__ b2, float* __restrict__ o){
  int i = blockIdx.x*blockDim.x + threadIdx.x;
  if (i >= NS*NO) return;
  int r = i / NO, c = i - r*NO;
  float acc = b2[c];
  const float* t1 = st1 + (size_t)r*DD;
  const float* wr = w2 + (size_t)c*DD;
  for (int k=0; k<DD; ++k) acc += t1[k]*wr[k];
  o[i] = acc;
}

// ---------- Set2Set (1 step, zero init state -> q is graph-independent) ----------
__global__ void k_qvec(const float* __restrict__ bih, const float* __restrict__ bhh, float* __restrict__ qv){
  int g = threadIdx.x;
  float gi = bih[g] + bhh[g];
  float gg = bih[128+g] + bhh[128+g];
  float go = bih[192+g] + bhh[192+g];
  float c = sg(gi)*tanhf(gg);
  qv[g] = sg(go)*tanhf(c);
}
__global__ __launch_bounds__(256) void k_e(const float* __restrict__ h, const float* __restrict__ qv,
                    const int* __restrict__ batch, float* __restrict__ evec, unsigned* __restrict__ emax){
  int n = (blockIdx.x*blockDim.x + threadIdx.x) >> 6;
  int lane = threadIdx.x & 63;
  if (n >= NN) return;
  float p = h[(size_t)n*DD + lane] * qv[lane];
  #pragma unroll
  for (int off=32; off; off>>=1) p += __shfl_xor(p, off);
  if (lane == 0){
    evec[n] = p;
    atomicMax(&emax[batch[n]], fenc(p));
  }
}
__global__ __launch_bounds__(256) void k_exden(float* __restrict__ evec, const unsigned* __restrict__ emax,
                        const int* __restrict__ batch, float* __restrict__ denom){
  int n = blockIdx.x*blockDim.x + threadIdx.x;
  if (n >= NN) return;
  float m = fdec(emax[batch[n]]);
  float ex = expf(evec[n] - m);
  evec[n] = ex;
  atomicAdd(&denom[batch[n]], ex);
}
__global__ __launch_bounds__(256) void k_rvec(const float* __restrict__ h, const float* __restrict__ evec,
                       const float* __restrict__ denom, const int* __restrict__ batch,
                       float* __restrict__ rvec){
  int n = (blockIdx.x*blockDim.x + threadIdx.x) >> 6;
  int lane = threadIdx.x & 63;
  if (n >= NN) return;
  int b = batch[n];
  float a = evec[n] / denom[b];
  atomicAdd(&rvec[(size_t)b*DD + lane], a * h[(size_t)n*DD + lane]);
}
__global__ __launch_bounds__(256) void k_gout(const float* __restrict__ qv, const float* __restrict__ rvec,
                       const float* __restrict__ lw, const float* __restrict__ lb, float* __restrict__ o){
  int t = blockIdx.x*blockDim.x + threadIdx.x;
  if (t >= NGG*2) return;
  int g = t >> 1, c = t & 1;
  float acc = lb[c];
  for (int j=0; j<DD; ++j) acc += qv[j]*lw[c*128 + j];
  for (int j=0; j<DD; ++j) acc += rvec[(size_t)g*DD + j]*lw[c*128 + 64 + j];
  o[g*2 + c] = acc;
}

// ---------- host ----------
extern "C" void kernel_launch(void* const* d_in, const int* in_sizes, int n_in,
                              void* d_out_, int out_size, void* d_ws, size_t ws_size,
                              hipStream_t stream){
  const float* x        = (const float*)d_in[0];
  const int*   ei       = (const int*)d_in[1];
  const float* eattr    = (const float*)d_in[2];
  const int*   jbidx    = (const int*)d_in[3];
  const int*   stidx    = (const int*)d_in[4];
  const int*   batch    = (const int*)d_in[5];
  const float* lin0_w   = (const float*)d_in[6];
  const float* lin0_b   = (const float*)d_in[7];
  const float* net1_w   = (const float*)d_in[8];
  const float* net1_b   = (const float*)d_in[9];
  const float* net2_w   = (const float*)d_in[10];
  const float* net2_b   = (const float*)d_in[11];
  const float* conv_root= (const float*)d_in[12];
  const float* conv_b   = (const float*)d_in[13];
  const float* gru_wih  = (const float*)d_in[14];
  const float* gru_whh  = (const float*)d_in[15];
  const float* gru_bih  = (const float*)d_in[16];
  const float* gru_bhh  = (const float*)d_in[17];
  const float* n2s_w1   = (const float*)d_in[18];
  const float* n2s_b1   = (const float*)d_in[19];
  const float* n2s_w2   = (const float*)d_in[20];
  const float* n2s_b2   = (const float*)d_in[21];
  const float* n2j_w1   = (const float*)d_in[22];
  const float* n2j_b1   = (const float*)d_in[23];
  const float* n2j_w2   = (const float*)d_in[24];
  const float* n2j_b2   = (const float*)d_in[25];
  const float* lstm_bih = (const float*)d_in[28];
  const float* lstm_bhh = (const float*)d_in[29];
  const float* lout_w   = (const float*)d_in[30];
  const float* lout_b   = (const float*)d_in[31];
  float* out = (float*)d_out_;

  const int* src = ei;
  const int* dst = ei + NE;

  char* ws = (char*)d_ws;
  size_t off = 0;
  auto alloc = [&](size_t bytes)->void*{
    void* p = ws + off; off = (off + bytes + 255) & ~(size_t)255; return p;
  };
  float* h    = (float*)alloc((size_t)NN*DD*4);
  float* aggr = (float*)alloc((size_t)NN*DD*4);
  unsigned short* e1   = (unsigned short*)alloc((size_t)EPAD*DD*2);
  unsigned short* w2bf = (unsigned short*)alloc((size_t)4096*DD*2);
  float* wihT = (float*)alloc((size_t)DD*192*4);
  float* whhT = (float*)alloc((size_t)DD*192*4);
  float* w1jT = (float*)alloc((size_t)DD*DD*4);
  float* w1sT = (float*)alloc((size_t)DD*DD*4);
  float* invd = (float*)alloc((size_t)NN*4);
  float* evec = (float*)alloc((size_t)NN*4);
  unsigned* emax = (unsigned*)alloc((size_t)NGG*4);
  float* denom = (float*)alloc((size_t)NGG*4);
  float* rvec  = (float*)alloc((size_t)NGG*DD*4);
  float* qv    = (float*)alloc((size_t)DD*4);
  float* jtmp  = (float*)alloc((size_t)NJ*2*4);
  float* st1   = (float*)alloc((size_t)NS*DD*4);

  size_t rem = ws_size > off ? ws_size - off : 0;
  const size_t fullW = (size_t)EPAD*4096*2;
  bool big; int CH;
  if (rem >= fullW){ big = true; CH = EPAD; }
  else {
    big = false;
    size_t che = rem / ((size_t)4096*2);
    CH = (int)((che/128)*128);
    if (CH < 128) CH = 128;
    if (CH > EPAD) CH = EPAD;
  }
  unsigned short* wedge = (unsigned short*)(ws + off);

  // ---- setup ----
  hipMemsetAsync(invd, 0, (size_t)NN*4, stream);   // used as deg accumulator first
  k_lin0<<<6250, 256, 0, stream>>>(x, lin0_w, lin0_b, h);
  k_e1<<<25024, 256, 0, stream>>>(eattr, net1_w, net1_b, e1);
  k_cast<<<1024, 256, 0, stream>>>(net2_w, w2bf);
  k_tr<<<48, 256, 0, stream>>>(gru_wih, wihT, 192, 64);
  k_tr<<<48, 256, 0, stream>>>(gru_whh, whhT, 192, 64);
  k_tr<<<16, 256, 0, stream>>>(n2j_w1, w1jT, 64, 64);
  k_tr<<<16, 256, 0, stream>>>(n2s_w1, w1sT, 64, 64);
  k_deg<<<391, 256, 0, stream>>>(dst, invd);
  k_invd<<<98, 256, 0, stream>>>(invd);

  if (big)
    k_gemm<<<dim3(EPAD/128, 64), 256, 0, stream>>>(e1, w2bf, net2_b, wedge, 0);

  // ---- 6 message-passing + GRU iterations ----
  for (int it=0; it<6; ++it){
    hipMemsetAsync(aggr, 0, (size_t)NN*DD*4, stream);
    if (big){
      k_msg<<<EPAD/4, 256, 0, stream>>>(wedge, h, src, dst, aggr, 0, EPAD);
    } else {
      for (int cs=0; cs<EPAD; cs+=CH){
        int cc = (EPAD - cs) < CH ? (EPAD - cs) : CH;
        k_gemm<<<dim3(cc/128, 64), 256, 0, stream>>>(e1, w2bf, net2_b, wedge, cs);
        k_msg<<<cc/4, 256, 0, stream>>>(wedge, h, src, dst, aggr, cs, cc);
      }
    }
    k_gru<<<782, 256, 0, stream>>>(h, aggr, invd, conv_root, conv_b, wihT, whhT, gru_bih, gru_bhh);
  }

  // ---- heads ----
  k_jbond<<<512, 256, 0, stream>>>(h, jbidx, w1jT, n2j_b1, n2j_w2, n2j_b2, jtmp);
  k_jmean<<<4, 256, 0, stream>>>(jtmp, out + NGG*2 + NS*NO);
  k_stem1<<<512, 256, 0, stream>>>(h, stidx, w1sT, n2s_b1, st1);
  k_stem2<<<840, 256, 0, stream>>>(st1, n2s_w2, n2s_b2, out + NGG*2);

  // ---- Set2Set ----
  hipMemsetAsync(emax, 0, (size_t)NGG*4, stream);   // 0 < fenc(x) for all finite x
  hipMemsetAsync(denom, 0, (size_t)NGG*4, stream);
  hipMemsetAsync(rvec, 0, (size_t)NGG*DD*4, stream);
  k_qvec<<<1, 64, 0, stream>>>(lstm_bih, lstm_bhh, qv);
  k_e<<<6250, 256, 0, stream>>>(h, qv, batch, evec, emax);
  k_exden<<<98, 256, 0, stream>>>(evec, emax, batch, denom);
  k_rvec<<<6250, 256, 0, stream>>>(h, evec, denom, batch, rvec);
  k_gout<<<4, 256, 0, stream>>>(qv, rvec, lout_w, lout_b, out);
}

// Round 2
// 1671.990 us; speedup vs baseline: 2.1919x; 2.1919x over previous
//
#include <hip/hip_runtime.h>
#include <stdint.h>
#include <stddef.h>

#define NN 25000     // nodes
#define NE 100000    // edges
#define EPAD 100096  // multiple of 64 >= NE
#define FEAT 16
#define DD 64
#define NGG 512
#define NJ 1024
#define NS 2048
#define NO 105
#define SLOPE 0.01f
#define TEB 64       // edges per tile (one wave per block)

typedef short bf8 __attribute__((ext_vector_type(8)));   // 8 bf16 raw bits (4 VGPR)
typedef float f32x4 __attribute__((ext_vector_type(4)));

__device__ __forceinline__ float lk(float v){ return v > 0.f ? v : SLOPE*v; }
__device__ __forceinline__ unsigned short f2bf(float f){
  unsigned int x = __float_as_uint(f);
  x += 0x7fffu + ((x>>16)&1u);           // round-to-nearest-even
  return (unsigned short)(x>>16);
}
__device__ __forceinline__ float bf2f(unsigned short u){ return __uint_as_float(((unsigned int)u)<<16); }
__device__ __forceinline__ float sg(float x){ return 1.f/(1.f+expf(-x)); }
// order-preserving float<->uint encoding for atomicMax-based segment max
__device__ __forceinline__ unsigned fenc(float f){ unsigned u = __float_as_uint(f); return (u & 0x80000000u) ? ~u : (u | 0x80000000u); }
__device__ __forceinline__ float fdec(unsigned k){ unsigned u = (k & 0x80000000u) ? (k ^ 0x80000000u) : ~k; return __uint_as_float(u); }

// ---------- setup kernels ----------

__global__ __launch_bounds__(256) void k_lin0(const float* __restrict__ x, const float* __restrict__ w,
                       const float* __restrict__ b, float* __restrict__ h){
  int wid = (blockIdx.x*blockDim.x + threadIdx.x) >> 6;
  int lane = threadIdx.x & 63;
  if (wid >= NN) return;
  float xv = lane < FEAT ? x[wid*FEAT + lane] : 0.f;
  float acc = b[lane];
  #pragma unroll
  for (int f=0; f<FEAT; ++f) acc += __shfl(xv, f) * w[lane*FEAT + f];
  h[wid*DD + lane] = lk(acc);
}

// e1 = bf16(leaky(edge_attr @ net1_w.T + net1_b)); zero-pads tail edges up to EPAD
__global__ __launch_bounds__(256) void k_e1(const float* __restrict__ ea, const float* __restrict__ w,
                     const float* __restrict__ b, unsigned short* __restrict__ e1){
  int t = blockIdx.x*blockDim.x + threadIdx.x;   // t = e*64 + k
  int e = t >> 6, k = t & 63;
  float acc = 0.f;
  if (e < NE){
    acc = b[k];
    #pragma unroll
    for (int a=0; a<4; ++a) acc += ea[e*4+a] * w[k*4+a];
    acc = lk(acc);
  }
  e1[t] = f2bf(acc);
}

// bf16 cast of net2_w [4096][64]
__global__ __launch_bounds__(256) void k_cast(const float* __restrict__ w, unsigned short* __restrict__ o){
  int t = blockIdx.x*blockDim.x + threadIdx.x;
  o[t] = f2bf(w[t]);
}

// b2r[o*64+i] = bf16(net2_b[i*64+o])
__global__ __launch_bounds__(256) void k_b2r(const float* __restrict__ b2, unsigned short* __restrict__ o){
  int t = blockIdx.x*blockDim.x + threadIdx.x;
  if (t >= 4096) return;
  int oo = t >> 6, i = t & 63;
  o[oo*64 + i] = f2bf(b2[i*64 + oo]);
}

// generic transpose: T[c*R + r] = M[r*C + c]
__global__ __launch_bounds__(256) void k_tr(const float* __restrict__ m, float* __restrict__ t, int R, int C){
  int i = blockIdx.x*blockDim.x + threadIdx.x;
  if (i >= R*C) return;
  int r = i / C, c = i - r*C;
  t[c*R + r] = m[i];
}

__global__ __launch_bounds__(256) void k_deg(const int* __restrict__ dst, float* __restrict__ deg){
  int e = blockIdx.x*blockDim.x + threadIdx.x;
  if (e < NE) atomicAdd(&deg[dst[e]], 1.f);
}
__global__ __launch_bounds__(256) void k_invd(float* __restrict__ d){
  int n = blockIdx.x*blockDim.x + threadIdx.x;
  if (n < NN) d[n] = d[n] > 0.f ? 1.f/d[n] : 0.f;
}

// ---------- fused edge message: aggr[dst[e]] += h[src[e]] @ (e1[e]@W2^T + b2).reshape(64,64) ----------
// One wave per 64-edge tile. Slab loop over i (the "in" dim): temp = MFMA(e1, W2 rows i*64..i*64+63),
// macc += h[e][i] * temp. Bias handled by one extra MFMA pair: macc_init = MFMA(bf16(h), b2r).
// MFMA 16x16x32 bf16: A row=lane&15, k=kc*32+(lane>>4)*8+j ; B col=lane&15 same k; C/D col=lane&15,row=(lane>>4)*4+j
__global__ __launch_bounds__(64) void k_fused(const unsigned short* __restrict__ e1,
                                              const unsigned short* __restrict__ w2bf,
                                              const unsigned short* __restrict__ b2r,
                                              const float* __restrict__ h,
                                              const int* __restrict__ src, const int* __restrict__ dst,
                                              float* __restrict__ aggr){
  __shared__ float hT[64][68];    // hT[i][er] = h[src[e0+er]][i]; pad 68 (272B rows, 16B aligned)
  int lane = threadIdx.x;
  int e0 = blockIdx.x * TEB;
  int r16 = lane & 15, kg = lane >> 4;

  // stage transposed h_src tile (one coalesced row read per edge)
  for (int er = 0; er < TEB; ++er){
    int e = e0 + er;
    int s = (e < NE) ? src[e] : 0;
    hT[lane][er] = h[(size_t)s*DD + lane];
  }
  __syncthreads();

  // A-fragments: e1 (main) and bf16(h) (bias), once per tile
  bf8 af[4][2], hbf[4][2];
  #pragma unroll
  for (int mt=0; mt<4; ++mt){
    int e = e0 + mt*16 + r16;
    af[mt][0] = *(const bf8*)(e1 + (size_t)e*DD + kg*8);
    af[mt][1] = *(const bf8*)(e1 + (size_t)e*DD + 32 + kg*8);
    int s = (e < NE) ? src[e] : 0;
    const float* hr = h + (size_t)s*DD + kg*8;
    #pragma unroll
    for (int kc=0; kc<2; ++kc){
      const float* q = hr + kc*32;
      bf8 f;
      #pragma unroll
      for (int j=0; j<8; ++j) f[j] = (short)f2bf(q[j]);
      hbf[mt][kc] = f;
    }
  }

  const f32x4 zero4 = {0.f,0.f,0.f,0.f};
  f32x4 macc[4][4];
  {
    bf8 bb[4][2];
    #pragma unroll
    for (int n=0; n<4; ++n)
      #pragma unroll
      for (int kc=0; kc<2; ++kc)
        bb[n][kc] = *(const bf8*)(b2r + (size_t)(n*16 + r16)*DD + kc*32 + kg*8);
    #pragma unroll
    for (int mt=0; mt<4; ++mt)
      #pragma unroll
      for (int n=0; n<4; ++n){
        f32x4 t = __builtin_amdgcn_mfma_f32_16x16x32_bf16(hbf[mt][0], bb[n][0], zero4, 0,0,0);
        macc[mt][n] = __builtin_amdgcn_mfma_f32_16x16x32_bf16(hbf[mt][1], bb[n][1], t, 0,0,0);
      }
  }

  bf8 Ba[4][2], Bb[4][2];
  auto loadB = [&](bf8 (&B)[4][2], int sl){
    const unsigned short* wp = w2bf + (size_t)sl*4096;
    #pragma unroll
    for (int n=0; n<4; ++n)
      #pragma unroll
      for (int kc=0; kc<2; ++kc)
        B[n][kc] = *(const bf8*)(wp + (size_t)(n*16 + r16)*DD + kc*32 + kg*8);
  };
  auto body = [&](bf8 (&B)[4][2], int sl){
    #pragma unroll
    for (int mt=0; mt<4; ++mt){
      f32x4 s4 = *(const f32x4*)&hT[sl][mt*16 + kg*4];
      #pragma unroll
      for (int n=0; n<4; ++n){
        f32x4 t = __builtin_amdgcn_mfma_f32_16x16x32_bf16(af[mt][0], B[n][0], zero4, 0,0,0);
        t = __builtin_amdgcn_mfma_f32_16x16x32_bf16(af[mt][1], B[n][1], t, 0,0,0);
        macc[mt][n] += s4 * t;
      }
    }
  };

  loadB(Ba, 0);
  for (int sl = 0; sl < 64; sl += 2){
    loadB(Bb, sl+1);
    body(Ba, sl);
    loadB(Ba, (sl+2 < 64) ? sl+2 : 63);
    body(Bb, sl+1);
  }

  // scatter-add into aggr
  #pragma unroll
  for (int mt=0; mt<4; ++mt)
    #pragma unroll
    for (int j=0; j<4; ++j){
      int e = e0 + mt*16 + kg*4 + j;
      if (e < NE){
        int d2 = dst[e];
        float* ap = aggr + (size_t)d2*DD + r16;
        atomicAdd(ap,      macc[mt][0][j]);
        atomicAdd(ap + 16, macc[mt][1][j]);
        atomicAdd(ap + 32, macc[mt][2][j]);
        atomicAdd(ap + 48, macc[mt][3][j]);
      }
    }
}

// ---------- fused NNConv-root + GRU ----------
#define NB 8
__global__ __launch_bounds__(256) void k_gru(float* __restrict__ h, const float* __restrict__ aggr,
                      const float* __restrict__ invd,
                      const float* __restrict__ cr, const float* __restrict__ cb,
                      const float* __restrict__ wihT, const float* __restrict__ whhT,
                      const float* __restrict__ bih, const float* __restrict__ bhh){
  int wid = (blockIdx.x*blockDim.x + threadIdx.x) >> 6;
  int lane = threadIdx.x & 63;
  int nb0 = wid * NB;
  if (nb0 >= NN) return;
  int cnt = NN - nb0 < NB ? NN - nb0 : NB;

  float hreg[NB], mreg[NB], mac[NB];
  #pragma unroll
  for (int t=0; t<NB; ++t){ hreg[t] = (t<cnt) ? h[(size_t)(nb0+t)*DD + lane] : 0.f; mac[t]=0.f; }
  for (int i=0; i<DD; ++i){
    float crv = cr[i*DD + lane];
    #pragma unroll
    for (int t=0; t<NB; ++t) mac[t] += __shfl(hreg[t], i) * crv;
  }
  #pragma unroll
  for (int t=0; t<NB; ++t){
    if (t < cnt){
      float id = invd[nb0+t];
      mreg[t] = lk(aggr[(size_t)(nb0+t)*DD + lane]*id + mac[t] + cb[lane]);
    } else mreg[t] = 0.f;
  }
  float air[NB]={}, aiz[NB]={}, ain[NB]={}, ahr[NB]={}, ahz[NB]={}, ahn[NB]={};
  for (int i=0; i<DD; ++i){
    float w0 = wihT[i*192 + lane], w1 = wihT[i*192 + 64 + lane], w2 = wihT[i*192 + 128 + lane];
    float v0 = whhT[i*192 + lane], v1 = whhT[i*192 + 64 + lane], v2 = whhT[i*192 + 128 + lane];
    #pragma unroll
    for (int t=0; t<NB; ++t){
      float mi = __shfl(mreg[t], i), hi = __shfl(hreg[t], i);
      air[t] += mi*w0; aiz[t] += mi*w1; ain[t] += mi*w2;
      ahr[t] += hi*v0; ahz[t] += hi*v1; ahn[t] += hi*v2;
    }
  }
  float bi0 = bih[lane], bi1 = bih[64+lane], bi2 = bih[128+lane];
  float bh0 = bhh[lane], bh1 = bhh[64+lane], bh2 = bhh[128+lane];
  #pragma unroll
  for (int t=0; t<NB; ++t){
    if (t < cnt){
      float r = sg(air[t]+bi0 + ahr[t]+bh0);
      float z = sg(aiz[t]+bi1 + ahz[t]+bh1);
      float n = tanhf(ain[t]+bi2 + r*(ahn[t]+bh2));
      h[(size_t)(nb0+t)*DD + lane] = (1.f - z)*n + z*hreg[t];
    }
  }
}

// ---------- heads ----------
__global__ __launch_bounds__(256) void k_jbond(const float* __restrict__ h, const int* __restrict__ idx,
                        const float* __restrict__ w1T, const float* __restrict__ b1,
                        const float* __restrict__ w2, const float* __restrict__ b2,
                        float* __restrict__ jtmp){
  int wid = (blockIdx.x*blockDim.x + threadIdx.x) >> 6;
  int lane = threadIdx.x & 63;
  if (wid >= NJ*2) return;
  int a = idx[wid];
  float f = h[(size_t)a*DD + lane];
  float acc = b1[lane];
  for (int i=0; i<DD; ++i) acc += __shfl(f, i) * w1T[i*DD + lane];
  float p = lk(acc) * w2[lane];
  #pragma unroll
  for (int off=32; off; off>>=1) p += __shfl_xor(p, off);
  if (lane == 0) jtmp[wid] = p + b2[0];
}
__global__ __launch_bounds__(256) void k_jmean(const float* __restrict__ jtmp, float* __restrict__ o){
  int j = blockIdx.x*blockDim.x + threadIdx.x;
  if (j < NJ) o[j] = 0.5f*(jtmp[2*j] + jtmp[2*j+1]);
}
__global__ __launch_bounds__(256) void k_stem1(const float* __restrict__ h, const int* __restrict__ idx,
                        const float* __restrict__ w1T, const float* __restrict__ b1,
                        float* __restrict__ st1){
  int wid = (blockIdx.x*blockDim.x + threadIdx.x) >> 6;
  int lane = threadIdx.x & 63;
  if (wid >= NS) return;
  int a = idx[wid];
  float f = h[(size_t)a*DD + lane];
  float acc = b1[lane];
  for (int i=0; i<DD; ++i) acc += __shfl(f, i) * w1T[i*DD + lane];
  st1[(size_t)wid*DD + lane] = lk(acc);
}
__global__ __launch_bounds__(256) void k_stem2(const float* __restrict__ st1, const float* __restrict__ w2,
                        const float* __restrict__ b2, float* __restrict__ o){
  int i = blockIdx.x*blockDim.x + threadIdx.x;
  if (i >= NS*NO) return;
  int r = i / NO, c = i - r*NO;
  float acc = b2[c];
  const float* t1 = st1 + (size_t)r*DD;
  const float* wr = w2 + (size_t)c*DD;
  for (int k=0; k<DD; ++k) acc += t1[k]*wr[k];
  o[i] = acc;
}

// ---------- Set2Set (1 step, zero init state) ----------
__global__ void k_qvec(const float* __restrict__ bih, const float* __restrict__ bhh, float* __restrict__ qv){
  int g = threadIdx.x;
  float gi = bih[g] + bhh[g];
  float gg = bih[128+g] + bhh[128+g];
  float go = bih[192+g] + bhh[192+g];
  float c = sg(gi)*tanhf(gg);
  qv[g] = sg(go)*tanhf(c);
}
__global__ __launch_bounds__(256) void k_e(const float* __restrict__ h, const float* __restrict__ qv,
                    const int* __restrict__ batch, float* __restrict__ evec, unsigned* __restrict__ emax){
  int n = (blockIdx.x*blockDim.x + threadIdx.x) >> 6;
  int lane = threadIdx.x & 63;
  if (n >= NN) return;
  float p = h[(size_t)n*DD + lane] * qv[lane];
  #pragma unroll
  for (int off=32; off; off>>=1) p += __shfl_xor(p, off);
  if (lane == 0){
    evec[n] = p;
    atomicMax(&emax[batch[n]], fenc(p));
  }
}
__global__ __launch_bounds__(256) void k_exden(float* __restrict__ evec, const unsigned* __restrict__ emax,
                        const int* __restrict__ batch, float* __restrict__ denom){
  int n = blockIdx.x*blockDim.x + threadIdx.x;
  if (n >= NN) return;
  float m = fdec(emax[batch[n]]);
  float ex = expf(evec[n] - m);
  evec[n] = ex;
  atomicAdd(&denom[batch[n]], ex);
}
__global__ __launch_bounds__(256) void k_rvec(const float* __restrict__ h, const float* __restrict__ evec,
                       const float* __restrict__ denom, const int* __restrict__ batch,
                       float* __restrict__ rvec){
  int n = (blockIdx.x*blockDim.x + threadIdx.x) >> 6;
  int lane = threadIdx.x & 63;
  if (n >= NN) return;
  int b = batch[n];
  float a = evec[n] / denom[b];
  atomicAdd(&rvec[(size_t)b*DD + lane], a * h[(size_t)n*DD + lane]);
}
__global__ __launch_bounds__(256) void k_gout(const float* __restrict__ qv, const float* __restrict__ rvec,
                       const float* __restrict__ lw, const float* __restrict__ lb, float* __restrict__ o){
  int t = blockIdx.x*blockDim.x + threadIdx.x;
  if (t >= NGG*2) return;
  int g = t >> 1, c = t & 1;
  float acc = lb[c];
  for (int j=0; j<DD; ++j) acc += qv[j]*lw[c*128 + j];
  for (int j=0; j<DD; ++j) acc += rvec[(size_t)g*DD + j]*lw[c*128 + 64 + j];
  o[g*2 + c] = acc;
}

// ---------- host ----------
extern "C" void kernel_launch(void* const* d_in, const int* in_sizes, int n_in,
                              void* d_out_, int out_size, void* d_ws, size_t ws_size,
                              hipStream_t stream){
  const float* x        = (const float*)d_in[0];
  const int*   ei       = (const int*)d_in[1];
  const float* eattr    = (const float*)d_in[2];
  const int*   jbidx    = (const int*)d_in[3];
  const int*   stidx    = (const int*)d_in[4];
  const int*   batch    = (const int*)d_in[5];
  const float* lin0_w   = (const float*)d_in[6];
  const float* lin0_b   = (const float*)d_in[7];
  const float* net1_w   = (const float*)d_in[8];
  const float* net1_b   = (const float*)d_in[9];
  const float* net2_w   = (const float*)d_in[10];
  const float* net2_b   = (const float*)d_in[11];
  const float* conv_root= (const float*)d_in[12];
  const float* conv_b   = (const float*)d_in[13];
  const float* gru_wih  = (const float*)d_in[14];
  const float* gru_whh  = (const float*)d_in[15];
  const float* gru_bih  = (const float*)d_in[16];
  const float* gru_bhh  = (const float*)d_in[17];
  const float* n2s_w1   = (const float*)d_in[18];
  const float* n2s_b1   = (const float*)d_in[19];
  const float* n2s_w2   = (const float*)d_in[20];
  const float* n2s_b2   = (const float*)d_in[21];
  const float* n2j_w1   = (const float*)d_in[22];
  const float* n2j_b1   = (const float*)d_in[23];
  const float* n2j_w2   = (const float*)d_in[24];
  const float* n2j_b2   = (const float*)d_in[25];
  const float* lstm_bih = (const float*)d_in[28];
  const float* lstm_bhh = (const float*)d_in[29];
  const float* lout_w   = (const float*)d_in[30];
  const float* lout_b   = (const float*)d_in[31];
  float* out = (float*)d_out_;

  const int* src = ei;
  const int* dst = ei + NE;

  char* ws = (char*)d_ws;
  size_t off = 0;
  auto alloc = [&](size_t bytes)->void*{
    void* p = ws + off; off = (off + bytes + 255) & ~(size_t)255; return p;
  };
  float* h    = (float*)alloc((size_t)NN*DD*4);
  float* aggr = (float*)alloc((size_t)NN*DD*4);
  unsigned short* e1   = (unsigned short*)alloc((size_t)EPAD*DD*2);
  unsigned short* w2bf = (unsigned short*)alloc((size_t)4096*DD*2);
  unsigned short* b2r  = (unsigned short*)alloc((size_t)4096*2);
  float* wihT = (float*)alloc((size_t)DD*192*4);
  float* whhT = (float*)alloc((size_t)DD*192*4);
  float* w1jT = (float*)alloc((size_t)DD*DD*4);
  float* w1sT = (float*)alloc((size_t)DD*DD*4);
  float* invd = (float*)alloc((size_t)NN*4);
  float* evec = (float*)alloc((size_t)NN*4);
  unsigned* emax = (unsigned*)alloc((size_t)NGG*4);
  float* denom = (float*)alloc((size_t)NGG*4);
  float* rvec  = (float*)alloc((size_t)NGG*DD*4);
  float* qv    = (float*)alloc((size_t)DD*4);
  float* jtmp  = (float*)alloc((size_t)NJ*2*4);
  float* st1   = (float*)alloc((size_t)NS*DD*4);

  // ---- setup ----
  hipMemsetAsync(invd, 0, (size_t)NN*4, stream);   // deg accumulator first
  k_lin0<<<6250, 256, 0, stream>>>(x, lin0_w, lin0_b, h);
  k_e1<<<25024, 256, 0, stream>>>(eattr, net1_w, net1_b, e1);
  k_cast<<<1024, 256, 0, stream>>>(net2_w, w2bf);
  k_b2r<<<16, 256, 0, stream>>>(net2_b, b2r);
  k_tr<<<48, 256, 0, stream>>>(gru_wih, wihT, 192, 64);
  k_tr<<<48, 256, 0, stream>>>(gru_whh, whhT, 192, 64);
  k_tr<<<16, 256, 0, stream>>>(n2j_w1, w1jT, 64, 64);
  k_tr<<<16, 256, 0, stream>>>(n2s_w1, w1sT, 64, 64);
  k_deg<<<391, 256, 0, stream>>>(dst, invd);
  k_invd<<<98, 256, 0, stream>>>(invd);

  // ---- 6 message-passing + GRU iterations (Wedge never materialized) ----
  for (int it=0; it<6; ++it){
    hipMemsetAsync(aggr, 0, (size_t)NN*DD*4, stream);
    k_fused<<<EPAD/TEB, 64, 0, stream>>>(e1, w2bf, b2r, h, src, dst, aggr);
    k_gru<<<782, 256, 0, stream>>>(h, aggr, invd, conv_root, conv_b, wihT, whhT, gru_bih, gru_bhh);
  }

  // ---- heads ----
  k_jbond<<<512, 256, 0, stream>>>(h, jbidx, w1jT, n2j_b1, n2j_w2, n2j_b2, jtmp);
  k_jmean<<<4, 256, 0, stream>>>(jtmp, out + NGG*2 + NS*NO);
  k_stem1<<<512, 256, 0, stream>>>(h, stidx, w1sT, n2s_b1, st1);
  k_stem2<<<840, 256, 0, stream>>>(st1, n2s_w2, n2s_b2, out + NGG*2);

  // ---- Set2Set ----
  hipMemsetAsync(emax, 0, (size_t)NGG*4, stream);
  hipMemsetAsync(denom, 0, (size_t)NGG*4, stream);
  hipMemsetAsync(rvec, 0, (size_t)NGG*DD*4, stream);
  k_qvec<<<1, 64, 0, stream>>>(lstm_bih, lstm_bhh, qv);
  k_e<<<6250, 256, 0, stream>>>(h, qv, batch, evec, emax);
  k_exden<<<98, 256, 0, stream>>>(evec, emax, batch, denom);
  k_rvec<<<6250, 256, 0, stream>>>(h, evec, denom, batch, rvec);
  k_gout<<<4, 256, 0, stream>>>(qv, rvec, lout_w, lout_b, out);
}